// Round 2
// baseline (100.005 us; speedup 1.0000x reference)
//
#include <hip/hip_runtime.h>

// SpectralConv2d: B=2,L=8,C=64,H=64,W=33, M1=M2=16
// Round 2: occupancy + XCD locality.
//  - 1024 compute blocks: group g=(corner,xrow,oq8) x member blq(4).
//    XCD-aware bid mapping: the 4 blq blocks sharing one weight slice get
//    bids = same (mod 8) -> same XCD L2 (weights fetched from HBM once,
//    3/4 of in-loop weight loads are L2 hits instead of L3).
//  - c-split: thread = (yq4, blj4, ol8, ch2); each thread sums half the
//    c range (32 iters); halves combined via 4KB LDS scratch at the end.
//    -> 16 waves/CU (4/SIMD) instead of 8 (2/SIMD): latency hidden by TLP.
//  - __launch_bounds__(256,4) caps VGPR at 128 so 4 waves/SIMD fit.
//  - inner loop per c: 2 aligned global dwordx4 (w) + 2 ds_read_b128 (x)
//    + 16 FMA; unroll 4.
//  - zero-fill: identical coverage to round-1 (verified), re-partitioned:
//    per-block y-tails for 8 o x 4 bl, middle rows h in [16,48) in 2048
//    fill blocks.

constexpr int Cc    = 64;
constexpr int Ww    = 33;
constexpr int HW    = 64 * Ww;        // 2112
constexpr int PLANE = Cc * HW;        // 135168
constexpr int TOT   = 16 * PLANE;     // 2162688 (elements in real half)
constexpr int WSTR  = Cc * 16 * 16;   // 16384: o-stride in weight tensor

__global__ __launch_bounds__(256, 4) void spectral_fused_kernel(
    const float* __restrict__ xr, const float* __restrict__ xi,
    const float* __restrict__ wr1, const float* __restrict__ wi1,
    const float* __restrict__ wr2, const float* __restrict__ wi2,
    float* __restrict__ out)
{
    const int bid = blockIdx.x;
    const int t   = threadIdx.x;

    if (bid < 1024) {
        // ---- XCD-grouped decode: bid = slot*8 + xcd; member blq = slot&3 ----
        const int xcd = bid & 7;
        const int s   = bid >> 3;          // [0,128)
        const int blq = s & 3;             // weight-sharing member
        const int g   = (s >> 2) * 8 + xcd; // group [0,256) = (corner,xrow,oq)
        const int oq     = g & 7;
        const int xrow   = (g >> 3) & 15;
        const int corner = g >> 7;
        const int xin    = corner ? (48 + xrow) : xrow;
        const float* wr  = corner ? wr2 : wr1;
        const float* wi  = corner ? wi2 : wi1;

        // [r(2)][c(64)][blj(4)][y(16)] floats = 8192 floats = 32 KB
        __shared__ __align__(16) float xs[8192];

        // ---- stage x slice: coalesced scalar loads (rows are 132B-strided) ----
        {
            const int y  = t & 15;
            const int wb = (t >> 4) & 3;
            const int cg = t >> 6;
            const int src_base = (blq * 4 + wb) * PLANE + xin * Ww + y;
            #pragma unroll
            for (int k = 0; k < 32; ++k) {
                const int r = k >> 4;
                const int c = ((k & 15) << 2) | cg;
                const float* src = (r ? xi : xr) + (size_t)src_base + c * HW;
                xs[r * 4096 + c * 64 + wb * 16 + y] = *src;
            }
        }
        __syncthreads();

        // ---- compute: thread = (yq, blj, ol, ch) ----
        const int yq  = t & 3;
        const int blj = (t >> 2) & 3;
        const int ol  = (t >> 4) & 7;
        const int ch  = t >> 7;            // c-half
        const int o   = oq * 8 + ol;
        const int bl  = blq * 4 + blj;
        const int c0  = ch * 32;

        const float* wrp = wr + o * WSTR + xrow * 16 + yq * 4 + c0 * 256;
        const float* wip = wi + o * WSTR + xrow * 16 + yq * 4 + c0 * 256;
        const float4* xsr = reinterpret_cast<const float4*>(xs) + blj * 4 + yq + c0 * 16;
        const float4* xsi = xsr + 1024;    // imag half (+4096 floats)

        float4 ar = make_float4(0.f, 0.f, 0.f, 0.f);
        float4 ai = make_float4(0.f, 0.f, 0.f, 0.f);

        #pragma unroll 4
        for (int c = 0; c < 32; ++c) {
            const float4 wre = *reinterpret_cast<const float4*>(wrp + c * 256);
            const float4 wim = *reinterpret_cast<const float4*>(wip + c * 256);
            const float4 a   = xsr[c * 16];
            const float4 b   = xsi[c * 16];
            ar.x = fmaf(a.x, wre.x, ar.x); ar.x = fmaf(-b.x, wim.x, ar.x);
            ai.x = fmaf(a.x, wim.x, ai.x); ai.x = fmaf( b.x, wre.x, ai.x);
            ar.y = fmaf(a.y, wre.y, ar.y); ar.y = fmaf(-b.y, wim.y, ar.y);
            ai.y = fmaf(a.y, wim.y, ai.y); ai.y = fmaf( b.y, wre.y, ai.y);
            ar.z = fmaf(a.z, wre.z, ar.z); ar.z = fmaf(-b.z, wim.z, ar.z);
            ai.z = fmaf(a.z, wim.z, ai.z); ai.z = fmaf( b.z, wre.z, ai.z);
            ar.w = fmaf(a.w, wre.w, ar.w); ar.w = fmaf(-b.w, wim.w, ar.w);
            ai.w = fmaf(a.w, wim.w, ai.w); ai.w = fmaf( b.w, wre.w, ai.w);
        }

        // ---- combine c-halves via LDS scratch (reuse xs after barrier) ----
        __syncthreads();
        if (ch) {
            float4* sc = reinterpret_cast<float4*>(xs) + (t - 128) * 2;
            sc[0] = ar; sc[1] = ai;
        }
        __syncthreads();
        if (!ch) {
            const float4* sc = reinterpret_cast<const float4*>(xs) + t * 2;
            const float4 br = sc[0], bi = sc[1];
            ar.x += br.x; ar.y += br.y; ar.z += br.z; ar.w += br.w;
            ai.x += bi.x; ai.y += bi.y; ai.z += bi.z; ai.w += bi.w;

            const size_t ob = (size_t)(bl * Cc + o) * HW + xin * Ww + yq * 4;
            out[ob + 0] = ar.x; out[ob + 1] = ar.y;
            out[ob + 2] = ar.z; out[ob + 3] = ar.w;
            out[TOT + ob + 0] = ai.x; out[TOT + ob + 1] = ai.y;
            out[TOT + ob + 2] = ai.z; out[TOT + ob + 3] = ai.w;
        }

        // ---- zero y in [16,33) tails: 8 o x 4 bl x 17 y x 2 ri = 1088 ----
        #pragma unroll
        for (int q = 0; q < 5; ++q) {
            const int k = t + q * 256;
            if (k < 1088) {
                const int ri   = k >= 544;
                const int rem  = ri ? (k - 544) : k;
                const int ol_  = rem / 68;            // local o (0..7)
                const int sub  = rem - ol_ * 68;      // 68 = 4 bl * 17 y
                const int blj_ = sub / 17;
                const int yy   = 16 + (sub - blj_ * 17);
                const size_t idx = (size_t)((blq * 4 + blj_) * Cc + oq * 8 + ol_) * HW
                                 + (size_t)xin * Ww + yy + (ri ? (size_t)TOT : 0);
                out[idx] = 0.f;
            }
        }
    } else {
        // ---- zero blocks: one per (ri, bl, o) plane, middle rows h in [16,48)
        // 1056 contiguous floats at plane*2112 + 528 -> 264 float4.
        const int p     = bid - 1024;         // [0, 2048)
        const int ri    = p >> 10;
        const int plane = p & 1023;           // bl*64 + o
        float4* dst = (float4*)(out + (size_t)ri * TOT + (size_t)plane * HW + 528);
        const float4 z = make_float4(0.f, 0.f, 0.f, 0.f);
        dst[t] = z;
        if (t < 8) dst[256 + t] = z;          // 264 = 256 + 8
    }
}

extern "C" void kernel_launch(void* const* d_in, const int* in_sizes, int n_in,
                              void* d_out, int out_size, void* d_ws, size_t ws_size,
                              hipStream_t stream) {
    const float* xr  = (const float*)d_in[0];
    const float* xi  = (const float*)d_in[1];
    const float* wr1 = (const float*)d_in[2];
    const float* wi1 = (const float*)d_in[3];
    const float* wr2 = (const float*)d_in[4];
    const float* wi2 = (const float*)d_in[5];
    float* out = (float*)d_out;

    spectral_fused_kernel<<<3072, 256, 0, stream>>>(xr, xi, wr1, wi1, wr2, wi2, out);
}

// Round 3
// 95.038 us; speedup vs baseline: 1.0523x; 1.0523x over previous
//
#include <hip/hip_runtime.h>

// SpectralConv2d: B=2,L=8,C=64,H=64,W=33, M1=M2=16
// Round 3: round-1 structure + intra-block c-split for occupancy.
//  - 512 compute blocks (natural order: oq4|blq4|xrow16|corner2), 512 thr.
//  - x corner slice staged in LDS ONCE per block (32KB), 16 loads/thread.
//  - thread = (yq4, blj4, ol16, ch2): ch halves the c range (32 iters);
//    halves combined via LDS scratch (xs reused). 8 waves/block,
//    2 blocks/CU -> 4 waves/SIMD (was 2): latency hidden by TLP.
//  - __launch_bounds__(512,4) caps VGPR at 128.
//  - inner loop per c: 2 aligned global dwordx4 (w) + 2 ds_read_b128 (x)
//    + 16 FMA; unroll 4.
//  - zero-fill coverage identical to round-1 (verified): per-block y-tails
//    (16 o x 4 bl x 17 y x 2 ri), middle rows h in [16,48) in fill blocks
//    (now 1024 blocks x 2 planes each).

constexpr int Cc    = 64;
constexpr int Ww    = 33;
constexpr int HW    = 64 * Ww;        // 2112
constexpr int PLANE = Cc * HW;        // 135168
constexpr int TOT   = 16 * PLANE;     // 2162688 (elements in real half)
constexpr int WSTR  = Cc * 16 * 16;   // 16384: o-stride in weight tensor

__global__ __launch_bounds__(512, 4) void spectral_fused_kernel(
    const float* __restrict__ xr, const float* __restrict__ xi,
    const float* __restrict__ wr1, const float* __restrict__ wi1,
    const float* __restrict__ wr2, const float* __restrict__ wi2,
    float* __restrict__ out)
{
    const int bid = blockIdx.x;
    const int t   = threadIdx.x;

    if (bid < 512) {
        // ---- compute blocks: oq(4) | blq(4) | xrow(16) | corner(2) ----
        const int oq     = bid & 3;
        const int blq    = (bid >> 2) & 3;
        const int xrow   = (bid >> 4) & 15;
        const int corner = bid >> 8;
        const int xin    = corner ? (48 + xrow) : xrow;
        const float* wr  = corner ? wr2 : wr1;
        const float* wi  = corner ? wi2 : wi1;

        // [r(2)][c(64)][blj(4)][y(16)] floats = 8192 floats = 32 KB
        __shared__ __align__(16) float xs[8192];

        // ---- stage x slice once: coalesced scalar loads, 16 per thread ----
        {
            const int y  = t & 15;          // 16 consecutive floats per row
            const int wb = (t >> 4) & 3;    // bl within block
            const int cg = t >> 6;          // wave id (0..7) -> c low bits
            const int src_base = (blq * 4 + wb) * PLANE + xin * Ww + y;
            #pragma unroll
            for (int k = 0; k < 16; ++k) {
                const int r = k >> 3;                 // 0: real, 1: imag
                const int c = ((k & 7) << 3) | cg;    // covers 0..63
                const float* src = (r ? xi : xr) + (size_t)src_base + c * HW;
                xs[r * 4096 + c * 64 + wb * 16 + y] = *src;
            }
        }
        __syncthreads();

        // ---- compute: thread = (yq, blj, ol, ch) ----
        const int yq  = t & 3;
        const int blj = (t >> 2) & 3;
        const int ol  = (t >> 4) & 15;
        const int ch  = t >> 8;            // c-half
        const int o   = oq * 16 + ol;
        const int bl  = blq * 4 + blj;
        const int c0  = ch * 32;

        const float* wrp = wr + o * WSTR + xrow * 16 + yq * 4 + c0 * 256;
        const float* wip = wi + o * WSTR + xrow * 16 + yq * 4 + c0 * 256;
        const float4* xsr = reinterpret_cast<const float4*>(xs) + blj * 4 + yq + c0 * 16;
        const float4* xsi = xsr + 1024;    // imag half (+4096 floats)

        float4 ar = make_float4(0.f, 0.f, 0.f, 0.f);
        float4 ai = make_float4(0.f, 0.f, 0.f, 0.f);

        #pragma unroll 4
        for (int c = 0; c < 32; ++c) {
            const float4 wre = *reinterpret_cast<const float4*>(wrp + c * 256);
            const float4 wim = *reinterpret_cast<const float4*>(wip + c * 256);
            const float4 a   = xsr[c * 16];
            const float4 b   = xsi[c * 16];
            ar.x = fmaf(a.x, wre.x, ar.x); ar.x = fmaf(-b.x, wim.x, ar.x);
            ai.x = fmaf(a.x, wim.x, ai.x); ai.x = fmaf( b.x, wre.x, ai.x);
            ar.y = fmaf(a.y, wre.y, ar.y); ar.y = fmaf(-b.y, wim.y, ar.y);
            ai.y = fmaf(a.y, wim.y, ai.y); ai.y = fmaf( b.y, wre.y, ai.y);
            ar.z = fmaf(a.z, wre.z, ar.z); ar.z = fmaf(-b.z, wim.z, ar.z);
            ai.z = fmaf(a.z, wim.z, ai.z); ai.z = fmaf( b.z, wre.z, ai.z);
            ar.w = fmaf(a.w, wre.w, ar.w); ar.w = fmaf(-b.w, wim.w, ar.w);
            ai.w = fmaf(a.w, wim.w, ai.w); ai.w = fmaf( b.w, wre.w, ai.w);
        }

        // ---- combine c-halves via LDS scratch (reuse xs after barrier) ----
        __syncthreads();                    // all reads of xs done
        if (ch) {
            float4* sc = reinterpret_cast<float4*>(xs) + (t - 256) * 2;
            sc[0] = ar; sc[1] = ai;
        }
        __syncthreads();
        if (!ch) {
            const float4* sc = reinterpret_cast<const float4*>(xs) + t * 2;
            const float4 br = sc[0], bi = sc[1];
            ar.x += br.x; ar.y += br.y; ar.z += br.z; ar.w += br.w;
            ai.x += bi.x; ai.y += bi.y; ai.z += bi.z; ai.w += bi.w;

            const size_t ob = (size_t)(bl * Cc + o) * HW + xin * Ww + yq * 4;
            out[ob + 0] = ar.x; out[ob + 1] = ar.y;
            out[ob + 2] = ar.z; out[ob + 3] = ar.w;
            out[TOT + ob + 0] = ai.x; out[TOT + ob + 1] = ai.y;
            out[TOT + ob + 2] = ai.z; out[TOT + ob + 3] = ai.w;
        }

        // ---- zero y in [16,33) tails: 16 o x 4 bl x 17 y x 2 ri = 2176 ----
        #pragma unroll
        for (int q = 0; q < 5; ++q) {
            const int k = t + q * 512;
            if (k < 2176) {
                const int ri   = k >= 1088;
                const int rem  = ri ? (k - 1088) : k;
                const int ol_  = rem / 68;            // local o (0..15)
                const int sub  = rem - ol_ * 68;      // 68 = 4 bl * 17 y
                const int blj_ = sub / 17;
                const int yy   = 16 + (sub - blj_ * 17);
                const size_t idx = (size_t)((blq * 4 + blj_) * Cc + oq * 16 + ol_) * HW
                                 + (size_t)xin * Ww + yy + (ri ? (size_t)TOT : 0);
                out[idx] = 0.f;
            }
        }
    } else {
        // ---- zero blocks: 1024 blocks, 2 (ri, bl, o)-planes each,
        //      middle rows h in [16,48): 1056 floats at plane*2112+528 ----
        const int p = bid - 512;              // [0, 1024)
        const float4 z = make_float4(0.f, 0.f, 0.f, 0.f);
        #pragma unroll
        for (int q = 0; q < 2; ++q) {
            const int j = t + q * 512;        // [0, 528) per plane pair
            if (j < 528) {
                const int pl  = p * 2 + (j >= 264);   // global plane [0,2048)
                const int off = j - (j >= 264 ? 264 : 0);
                const int ri  = pl >> 10;
                float4* dst = (float4*)(out + (size_t)ri * TOT
                                            + (size_t)(pl & 1023) * HW + 528);
                dst[off] = z;
            }
        }
    }
}

extern "C" void kernel_launch(void* const* d_in, const int* in_sizes, int n_in,
                              void* d_out, int out_size, void* d_ws, size_t ws_size,
                              hipStream_t stream) {
    const float* xr  = (const float*)d_in[0];
    const float* xi  = (const float*)d_in[1];
    const float* wr1 = (const float*)d_in[2];
    const float* wi1 = (const float*)d_in[3];
    const float* wr2 = (const float*)d_in[4];
    const float* wi2 = (const float*)d_in[5];
    float* out = (float*)d_out;

    spectral_fused_kernel<<<1536, 512, 0, stream>>>(xr, xi, wr1, wi1, wr2, wi2, out);
}